// Round 1
// baseline (810.271 us; speedup 1.0000x reference)
//
#include <hip/hip_runtime.h>

#define BATCH 256
#define DIM   2048
#define NMEM  65536
#define NCLUS 8192
#define TEMP  0.05f

typedef __attribute__((ext_vector_type(8))) short bf16x8;
typedef __attribute__((ext_vector_type(4))) float f32x4;
typedef __attribute__((ext_vector_type(4))) unsigned short u16x4;
typedef __attribute__((ext_vector_type(8))) unsigned short u16x8;

__device__ inline unsigned short f2bf(float f) {
    unsigned u = __float_as_uint(f);
    u += 0x7fffu + ((u >> 16) & 1u);   // RNE
    return (unsigned short)(u >> 16);
}
__device__ inline float bf2f(unsigned short u) {
    return __uint_as_float(((unsigned)u) << 16);
}

// --- counts per cluster + targets gather -------------------------------------
__global__ void k_init(const int* __restrict__ labels, const int* __restrict__ indexes,
                       int* __restrict__ nums, int* __restrict__ targets) {
    int gid = blockIdx.x * 256 + threadIdx.x;
    if (gid < NMEM) atomicAdd(&nums[labels[gid]], 1);
    if (gid < BATCH) targets[gid] = labels[indexes[gid]];
}

// --- exclusive prefix over NCLUS counts (1 block, 256 thr x 32 each) ---------
__global__ void k_scan(const int* __restrict__ nums, int* __restrict__ offs) {
    __shared__ int part[256];
    int t = threadIdx.x;
    int base = t * 32;
    int local[32];
    int s = 0;
    #pragma unroll
    for (int i = 0; i < 32; i++) { local[i] = s; s += nums[base + i]; }
    part[t] = s;
    __syncthreads();
    for (int d = 1; d < 256; d <<= 1) {
        int v = (t >= d) ? part[t - d] : 0;
        __syncthreads();
        part[t] += v;
        __syncthreads();
    }
    int cb = (t == 0) ? 0 : part[t - 1];
    #pragma unroll
    for (int i = 0; i < 32; i++) offs[base + i] = cb + local[i];
}

// --- scatter member indices per cluster --------------------------------------
__global__ void k_scatter(const int* __restrict__ labels, const int* __restrict__ offs,
                          int* __restrict__ cursor, int* __restrict__ order) {
    int n = blockIdx.x * 256 + threadIdx.x;
    int c = labels[n];
    int pos = atomicAdd(&cursor[c], 1);
    order[offs[c] + pos] = n;
}

// --- convert inputs fp32 -> bf16, K-chunk-swizzled for global_load_lds -------
// layout: chunk s (of 64, 32 k each): A_sw[s*8192 + r*32 + kk]
__global__ void k_convA(const float* __restrict__ inputs, unsigned short* __restrict__ A_sw) {
    int gid = blockIdx.x * 256 + threadIdx.x;   // 65536 threads, 8 elts each
    int e = gid * 8;
    int r = e >> 11;       // row (batch), 2048 per row
    int k = e & 2047;
    const float4* p = (const float4*)(inputs + (size_t)r * DIM + k);
    float4 f0 = p[0], f1 = p[1];
    u16x8 o;
    o[0] = f2bf(f0.x); o[1] = f2bf(f0.y); o[2] = f2bf(f0.z); o[3] = f2bf(f0.w);
    o[4] = f2bf(f1.x); o[5] = f2bf(f1.y); o[6] = f2bf(f1.z); o[7] = f2bf(f1.w);
    *(u16x8*)(A_sw + (size_t)(k >> 5) * (BATCH * 32) + r * 32 + (k & 31)) = o;
}

// --- GEMM: sims^T[n][b] (bf16) = features[n,:] . inputs[b,:] -----------------
// BM=256 (full batch), BN=64, BK=32; 4 waves, each 64(M)x64(N); 16x16x32 bf16 MFMA
__global__ __launch_bounds__(256) void k_gemm(const float* __restrict__ feats,
                                              const unsigned short* __restrict__ A_sw,
                                              unsigned short* __restrict__ sims_t) {
    __shared__ short As[BATCH * 32];   // 16 KB  [r][k], 64B row stride
    __shared__ short Bs[64 * 32];      //  4 KB  [n][k]
    int tid = threadIdx.x;
    int w = tid >> 6, l = tid & 63;
    int n0 = blockIdx.x * 64;
    int ar = l & 15, aq = l >> 4;

    f32x4 acc[4][4];
    #pragma unroll
    for (int i = 0; i < 4; i++)
        #pragma unroll
        for (int j = 0; j < 4; j++) acc[i][j] = (f32x4){0.f, 0.f, 0.f, 0.f};

    // B staging addressing: 8 threads per feature row, 2 row-passes of 32
    const float* fb = feats + (size_t)(n0 + (tid >> 3)) * DIM + (tid & 7) * 4;
    int brow = tid >> 3, bcol = (tid & 7) * 4;

    for (int s = 0; s < 64; s++) {
        __syncthreads();
        // stage A (bf16, pre-swizzled): 16 KB via global_load_lds x4/wave
        {
            const char* gbase = (const char*)A_sw + (size_t)s * 16384;
            #pragma unroll
            for (int i = 0; i < 4; i++) {
                int ofs = ((w << 2) + i) * 1024;
                __builtin_amdgcn_global_load_lds(
                    (const __attribute__((address_space(1))) void*)(gbase + ofs + l * 16),
                    (__attribute__((address_space(3))) void*)((char*)As + ofs),
                    16, 0, 0);
            }
        }
        // stage B: fp32 load + convert + LDS write
        {
            float4 v0 = *(const float4*)(fb + s * 32);
            float4 v1 = *(const float4*)(fb + (size_t)32 * DIM + s * 32);
            u16x4 b0, b1;
            b0[0] = f2bf(v0.x); b0[1] = f2bf(v0.y); b0[2] = f2bf(v0.z); b0[3] = f2bf(v0.w);
            b1[0] = f2bf(v1.x); b1[1] = f2bf(v1.y); b1[2] = f2bf(v1.z); b1[3] = f2bf(v1.w);
            *(u16x4*)&Bs[brow * 32 + bcol] = b0;
            *(u16x4*)&Bs[(brow + 32) * 32 + bcol] = b1;
        }
        __syncthreads();
        bf16x8 a[4], b[4];
        #pragma unroll
        for (int i = 0; i < 4; i++) a[i] = *(const bf16x8*)&As[(w * 64 + i * 16 + ar) * 32 + aq * 8];
        #pragma unroll
        for (int j = 0; j < 4; j++) b[j] = *(const bf16x8*)&Bs[(j * 16 + ar) * 32 + aq * 8];
        #pragma unroll
        for (int i = 0; i < 4; i++)
            #pragma unroll
            for (int j = 0; j < 4; j++)
                acc[i][j] = __builtin_amdgcn_mfma_f32_16x16x32_bf16(a[i], b[j], acc[i][j], 0, 0, 0);
    }
    // epilogue: C/D layout col=lane&15, row=(lane>>4)*4+reg; store bf16 sims^T
    #pragma unroll
    for (int i = 0; i < 4; i++) {
        int row = w * 64 + i * 16 + aq * 4;   // batch index
        #pragma unroll
        for (int j = 0; j < 4; j++) {
            int col = n0 + j * 16 + ar;        // memory-bank index
            f32x4 v = acc[i][j];
            u16x4 o;
            o[0] = f2bf(v[0]); o[1] = f2bf(v[1]); o[2] = f2bf(v[2]); o[3] = f2bf(v[3]);
            *(u16x4*)&sims_t[(size_t)col * BATCH + row] = o;
        }
    }
}

// --- per-cluster reduction: avg-exp + diag-exp -------------------------------
__global__ void k_reduce(const unsigned short* __restrict__ sims_t, const int* __restrict__ order,
                         const int* __restrict__ offs, const int* __restrict__ nums,
                         const int* __restrict__ targets, float* __restrict__ partial,
                         float* __restrict__ numval) {
    int c = blockIdx.x;
    int cnt = nums[c];
    if (cnt == 0) return;   // cmask = 0: contributes nothing
    int t = threadIdx.x;
    int off = offs[c];
    bool own = (targets[t] == c);
    float acc = 0.f, d2 = 0.f;
    for (int i = 0; i < cnt; i++) {
        int n = order[off + i];
        float s = bf2f(sims_t[(size_t)n * BATCH + t]);
        acc += s;
        if (own) d2 += s * s;
    }
    // avg logit = (sum sims / cnt) / TEMP ; diag = (sum sims^2) / TEMP
    float val = own ? __expf(d2 * (1.f / TEMP)) : __expf(acc / ((float)cnt * TEMP));
    if (own) numval[t] = val;                    // exactly one block owns each b
    atomicAdd(&partial[(c & 63) * BATCH + t], val);
}

// --- final loss --------------------------------------------------------------
__global__ void k_loss(const float* __restrict__ partial, const float* __restrict__ numval,
                       float* __restrict__ out) {
    __shared__ float red[256];
    int t = threadIdx.x;
    float tot = 0.f;
    #pragma unroll
    for (int p = 0; p < 64; p++) tot += partial[p * BATCH + t];
    float ls = -logf(numval[t] / (tot + 1e-6f) + 1e-6f);
    red[t] = ls;
    __syncthreads();
    for (int d = 128; d > 0; d >>= 1) {
        if (t < d) red[t] += red[t + d];
        __syncthreads();
    }
    if (t == 0) out[0] = red[0] / (float)BATCH;
}

extern "C" void kernel_launch(void* const* d_in, const int* in_sizes, int n_in,
                              void* d_out, int out_size, void* d_ws, size_t ws_size,
                              hipStream_t stream) {
    const float* inputs  = (const float*)d_in[0];   // [256, 2048]
    const int*   indexes = (const int*)d_in[1];     // [256]
    const float* feats   = (const float*)d_in[2];   // [65536, 2048]
    const int*   labels  = (const int*)d_in[3];     // [65536]
    float* out = (float*)d_out;

    char* ws = (char*)d_ws;
    size_t off = 0;
    unsigned short* sims_t = (unsigned short*)(ws + off); off += (size_t)NMEM * BATCH * 2;  // 32 MB
    unsigned short* A_sw   = (unsigned short*)(ws + off); off += (size_t)BATCH * DIM * 2;   // 1 MB
    int*   nums    = (int*)(ws + off);   off += NCLUS * 4;
    int*   cursor  = (int*)(ws + off);   off += NCLUS * 4;
    float* partial = (float*)(ws + off); off += 64 * BATCH * 4;
    int*   offs    = (int*)(ws + off);   off += NCLUS * 4;
    int*   order   = (int*)(ws + off);   off += (size_t)NMEM * 4;
    int*   targets = (int*)(ws + off);   off += BATCH * 4;
    float* numval  = (float*)(ws + off); off += BATCH * 4;

    // zero nums + cursor + partial (contiguous)
    hipMemsetAsync(nums, 0, NCLUS * 4 + NCLUS * 4 + 64 * BATCH * 4, stream);

    k_init   <<<NMEM / 256, 256, 0, stream>>>(labels, indexes, nums, targets);
    k_scan   <<<1, 256, 0, stream>>>(nums, offs);
    k_scatter<<<NMEM / 256, 256, 0, stream>>>(labels, offs, cursor, order);
    k_convA  <<<(BATCH * DIM / 8) / 256, 256, 0, stream>>>(inputs, A_sw);
    k_gemm   <<<NMEM / 64, 256, 0, stream>>>(feats, A_sw, sims_t);
    k_reduce <<<NCLUS, 256, 0, stream>>>(sims_t, order, offs, nums, targets, partial, numval);
    k_loss   <<<1, 256, 0, stream>>>(partial, numval, out);
}

// Round 2
// 807.590 us; speedup vs baseline: 1.0033x; 1.0033x over previous
//
#include <hip/hip_runtime.h>

#define BATCH 256
#define DIM   2048
#define NMEM  65536
#define NCLUS 8192
#define TEMP  0.05f

typedef __attribute__((ext_vector_type(8))) short bf16x8;
typedef __attribute__((ext_vector_type(4))) float f32x4;
typedef __attribute__((ext_vector_type(4))) unsigned short u16x4;
typedef __attribute__((ext_vector_type(8))) unsigned short u16x8;

__device__ inline unsigned short f2bf(float f) {
    unsigned u = __float_as_uint(f);
    u += 0x7fffu + ((u >> 16) & 1u);   // RNE
    return (unsigned short)(u >> 16);
}

// --- counts per cluster + targets gather -------------------------------------
__global__ void k_init(const int* __restrict__ labels, const int* __restrict__ indexes,
                       int* __restrict__ nums, int* __restrict__ targets) {
    int gid = blockIdx.x * 256 + threadIdx.x;
    if (gid < NMEM) atomicAdd(&nums[labels[gid]], 1);
    if (gid < BATCH) targets[gid] = labels[indexes[gid]];
}

// --- exclusive prefix over NCLUS counts (1 block, 256 thr x 32 each) ---------
__global__ void k_scan(const int* __restrict__ nums, int* __restrict__ offs) {
    __shared__ int part[256];
    int t = threadIdx.x;
    int base = t * 32;
    int local[32];
    int s = 0;
    #pragma unroll
    for (int i = 0; i < 32; i++) { local[i] = s; s += nums[base + i]; }
    part[t] = s;
    __syncthreads();
    for (int d = 1; d < 256; d <<= 1) {
        int v = (t >= d) ? part[t - d] : 0;
        __syncthreads();
        part[t] += v;
        __syncthreads();
    }
    int cb = (t == 0) ? 0 : part[t - 1];
    #pragma unroll
    for (int i = 0; i < 32; i++) offs[base + i] = cb + local[i];
}

// --- scatter member indices per cluster --------------------------------------
__global__ void k_scatter(const int* __restrict__ labels, const int* __restrict__ offs,
                          int* __restrict__ cursor, int* __restrict__ order) {
    int n = blockIdx.x * 256 + threadIdx.x;
    int c = labels[n];
    int pos = atomicAdd(&cursor[c], 1);
    order[offs[c] + pos] = n;
}

// --- convert inputs fp32 -> bf16, K-chunk-swizzled for global_load_lds -------
__global__ void k_convA(const float* __restrict__ inputs, unsigned short* __restrict__ A_sw) {
    int gid = blockIdx.x * 256 + threadIdx.x;   // 65536 threads, 8 elts each
    int e = gid * 8;
    int r = e >> 11;
    int k = e & 2047;
    const float4* p = (const float4*)(inputs + (size_t)r * DIM + k);
    float4 f0 = p[0], f1 = p[1];
    u16x8 o;
    o[0] = f2bf(f0.x); o[1] = f2bf(f0.y); o[2] = f2bf(f0.z); o[3] = f2bf(f0.w);
    o[4] = f2bf(f1.x); o[5] = f2bf(f1.y); o[6] = f2bf(f1.z); o[7] = f2bf(f1.w);
    *(u16x8*)(A_sw + (size_t)(k >> 5) * (BATCH * 32) + r * 32 + (k & 31)) = o;
}

// --- cluster-sum of feature rows: csum[c] = sum features[n], bf16 out --------
// one block per cluster; thread t owns columns t*8..t*8+7 (coalesced full row)
__global__ __launch_bounds__(256) void k_agg(const float* __restrict__ feats,
                                             const int* __restrict__ order,
                                             const int* __restrict__ offs,
                                             const int* __restrict__ nums,
                                             unsigned short* __restrict__ csum) {
    int c = blockIdx.x;
    int t = threadIdx.x;
    int cnt = nums[c], off = offs[c];
    float acc[8] = {0.f, 0.f, 0.f, 0.f, 0.f, 0.f, 0.f, 0.f};
    int nn = (cnt > 0) ? order[off] : 0;
    for (int i = 0; i < cnt; i++) {
        int ncur = nn;
        if (i + 1 < cnt) nn = order[off + i + 1];
        const float4* p = (const float4*)(feats + (size_t)ncur * DIM + t * 8);
        float4 a = p[0], b = p[1];
        acc[0] += a.x; acc[1] += a.y; acc[2] += a.z; acc[3] += a.w;
        acc[4] += b.x; acc[5] += b.y; acc[6] += b.z; acc[7] += b.w;
    }
    u16x8 o;
    #pragma unroll
    for (int j = 0; j < 8; j++) o[j] = f2bf(acc[j]);
    *(u16x8*)(csum + (size_t)c * DIM + t * 8) = o;
}

// --- GEMM2: simP[kc][c][b] = sum_k inputs[b][k]*csum[c][k] over K-chunk kc ---
// BM=256 (full batch), BN=64, K-chunk=512 (16 steps of 32); 4 waves x (64Mx64N)
__global__ __launch_bounds__(256) void k_gemm2(const unsigned short* __restrict__ csum,
                                               const unsigned short* __restrict__ A_sw,
                                               float* __restrict__ simP) {
    __shared__ short As[BATCH * 32];   // 16 KB  [b][k]
    __shared__ short Bs[64 * 32];      //  4 KB  [c][k]
    int tid = threadIdx.x;
    int w = tid >> 6, l = tid & 63;
    int n0 = blockIdx.x * 64;
    int kc = blockIdx.y;
    int ar = l & 15, aq = l >> 4;

    f32x4 acc[4][4];
    #pragma unroll
    for (int i = 0; i < 4; i++)
        #pragma unroll
        for (int j = 0; j < 4; j++) acc[i][j] = (f32x4){0.f, 0.f, 0.f, 0.f};

    // B staging: 4 threads per csum row (32 k as 4x8), lds dest = tid*16 bytes
    const char* bgbase = (const char*)(csum + (size_t)(n0 + (tid >> 2)) * DIM + (tid & 3) * 8);

    for (int ss = 0; ss < 16; ss++) {
        int s = kc * 16 + ss;
        __syncthreads();
        {   // stage A: 16 KB, pre-swizzled bf16, 4 x 1KB per wave
            const char* gbase = (const char*)A_sw + (size_t)s * 16384;
            #pragma unroll
            for (int i = 0; i < 4; i++) {
                int ofs = ((w << 2) + i) * 1024;
                __builtin_amdgcn_global_load_lds(
                    (const __attribute__((address_space(1))) void*)(gbase + ofs + l * 16),
                    (__attribute__((address_space(3))) void*)((char*)As + ofs),
                    16, 0, 0);
            }
        }
        {   // stage B: 4 KB bf16, 1 KB per wave, per-lane gather -> lane*16
            __builtin_amdgcn_global_load_lds(
                (const __attribute__((address_space(1))) void*)(bgbase + (size_t)s * 64),
                (__attribute__((address_space(3))) void*)((char*)Bs + w * 1024),
                16, 0, 0);
        }
        __syncthreads();
        bf16x8 a[4], b[4];
        #pragma unroll
        for (int i = 0; i < 4; i++) a[i] = *(const bf16x8*)&As[(w * 64 + i * 16 + ar) * 32 + aq * 8];
        #pragma unroll
        for (int j = 0; j < 4; j++) b[j] = *(const bf16x8*)&Bs[(j * 16 + ar) * 32 + aq * 8];
        #pragma unroll
        for (int i = 0; i < 4; i++)
            #pragma unroll
            for (int j = 0; j < 4; j++)
                acc[i][j] = __builtin_amdgcn_mfma_f32_16x16x32_bf16(a[i], b[j], acc[i][j], 0, 0, 0);
    }
    float* outp = simP + (size_t)kc * (NCLUS * BATCH);
    #pragma unroll
    for (int i = 0; i < 4; i++) {
        int row = w * 64 + i * 16 + aq * 4;    // batch index
        #pragma unroll
        for (int j = 0; j < 4; j++) {
            int col = n0 + j * 16 + ar;        // cluster index
            *(f32x4*)&outp[(size_t)col * BATCH + row] = acc[i][j];
        }
    }
}

// --- diag: d2[b] = sum over own-cluster members of (inputs[b].feats[n])^2 ----
__global__ void k_diag(const float* __restrict__ inputs, const float* __restrict__ feats,
                       const int* __restrict__ order, const int* __restrict__ offs,
                       const int* __restrict__ nums, const int* __restrict__ targets,
                       float* __restrict__ numval) {
    int b = blockIdx.x, t = threadIdx.x;
    int c = targets[b];
    int cnt = nums[c], off = offs[c];
    const float4* ip = (const float4*)(inputs + (size_t)b * DIM + t * 8);
    float4 x0 = ip[0], x1 = ip[1];
    __shared__ float red[256];
    float d2 = 0.f;
    for (int i = 0; i < cnt; i++) {
        int n = order[off + i];
        const float4* fp = (const float4*)(feats + (size_t)n * DIM + t * 8);
        float4 a = fp[0], bb = fp[1];
        float part = x0.x * a.x + x0.y * a.y + x0.z * a.z + x0.w * a.w
                   + x1.x * bb.x + x1.y * bb.y + x1.z * bb.z + x1.w * bb.w;
        red[t] = part;
        __syncthreads();
        for (int d = 128; d > 0; d >>= 1) {
            if (t < d) red[t] += red[t + d];
            __syncthreads();
        }
        if (t == 0) { float dot = red[0]; d2 += dot * dot; }
        __syncthreads();
    }
    if (t == 0) numval[b] = __expf(d2 * (1.f / TEMP));
}

// --- per-sample denominator partials over cluster chunks ---------------------
__global__ void k_reduce2(const float* __restrict__ simP, const int* __restrict__ nums,
                          const int* __restrict__ targets, const float* __restrict__ numval,
                          float* __restrict__ partial) {
    int p = blockIdx.x, t = threadIdx.x;
    int tgt = targets[t];
    float nv = numval[t];
    float tot = 0.f;
    const size_t CB = (size_t)NCLUS * BATCH;
    for (int j = 0; j < 128; j++) {
        int c = p * 128 + j;
        int cnt = nums[c];
        if (cnt == 0) continue;   // cmask: empty clusters excluded
        size_t a = (size_t)c * BATCH + t;
        float s = simP[a] + simP[CB + a] + simP[2 * CB + a] + simP[3 * CB + a];
        float val = (tgt == c) ? nv : __expf(s / ((float)cnt * TEMP));
        tot += val;
    }
    partial[p * 256 + t] = tot;
}

// --- final loss --------------------------------------------------------------
__global__ void k_loss(const float* __restrict__ partial, const float* __restrict__ numval,
                       float* __restrict__ out) {
    __shared__ float red[256];
    int t = threadIdx.x;
    float tot = 0.f;
    #pragma unroll
    for (int p = 0; p < 64; p++) tot += partial[p * 256 + t];
    float ls = -logf(numval[t] / (tot + 1e-6f) + 1e-6f);
    red[t] = ls;
    __syncthreads();
    for (int d = 128; d > 0; d >>= 1) {
        if (t < d) red[t] += red[t + d];
        __syncthreads();
    }
    if (t == 0) out[0] = red[0] / (float)BATCH;
}

extern "C" void kernel_launch(void* const* d_in, const int* in_sizes, int n_in,
                              void* d_out, int out_size, void* d_ws, size_t ws_size,
                              hipStream_t stream) {
    const float* inputs  = (const float*)d_in[0];   // [256, 2048]
    const int*   indexes = (const int*)d_in[1];     // [256]
    const float* feats   = (const float*)d_in[2];   // [65536, 2048]
    const int*   labels  = (const int*)d_in[3];     // [65536]
    float* out = (float*)d_out;

    char* ws = (char*)d_ws;
    size_t off = 0;
    unsigned short* csum = (unsigned short*)(ws + off); off += (size_t)NCLUS * DIM * 2;       // 32 MB
    unsigned short* A_sw = (unsigned short*)(ws + off); off += (size_t)BATCH * DIM * 2;       // 1 MB
    float* simP    = (float*)(ws + off); off += (size_t)4 * NCLUS * BATCH * 4;                // 32 MB
    int*   nums    = (int*)(ws + off);   off += NCLUS * 4;
    int*   cursor  = (int*)(ws + off);   off += NCLUS * 4;
    int*   offs    = (int*)(ws + off);   off += NCLUS * 4;
    int*   order   = (int*)(ws + off);   off += (size_t)NMEM * 4;
    int*   targets = (int*)(ws + off);   off += BATCH * 4;
    float* partial = (float*)(ws + off); off += 64 * BATCH * 4;
    float* numval  = (float*)(ws + off); off += BATCH * 4;

    hipMemsetAsync(nums, 0, NCLUS * 4 + NCLUS * 4, stream);   // nums + cursor

    k_init   <<<NMEM / 256, 256, 0, stream>>>(labels, indexes, nums, targets);
    k_scan   <<<1, 256, 0, stream>>>(nums, offs);
    k_scatter<<<NMEM / 256, 256, 0, stream>>>(labels, offs, cursor, order);
    k_convA  <<<(BATCH * DIM / 8) / 256, 256, 0, stream>>>(inputs, A_sw);
    k_agg    <<<NCLUS, 256, 0, stream>>>(feats, order, offs, nums, csum);
    dim3 g2(NCLUS / 64, 4);
    k_gemm2  <<<g2, 256, 0, stream>>>(csum, A_sw, simP);
    k_diag   <<<BATCH, 256, 0, stream>>>(inputs, feats, order, offs, nums, targets, numval);
    k_reduce2<<<64, 256, 0, stream>>>(simP, nums, targets, numval, partial);
    k_loss   <<<1, 256, 0, stream>>>(partial, numval, out);
}